// Round 4
// baseline (141.161 us; speedup 1.0000x reference)
//
#include <hip/hip_runtime.h>
#include <cstdint>
#include <cstddef>

// ---------------------------------------------------------------------------
// TripletFeatures: out[b,c,k] = S_mn * E[p+n,c] + (m!=n) * S_nm * E[p+m,c]
//   S_xy = sum_c E[p+x,c] * conj(E[p+x+y,c]),  E = E_real + i*E_imag, p=20
// R3: same as R2 (LDS-staged NB=32, float4 staging, unroll x2, nontemporal
// stores) with the compile fix: nontemporal vector store uses a native
// clang ext_vector_type(2) float instead of HIP_vector_type float2.
// ---------------------------------------------------------------------------

namespace {

constexpr int MM   = 41;   // M
constexpr int HALF = 20;   // M//2
constexpr int LIM  = 20;   // RHO*L//2
constexpr int CAP  = 256;

typedef float vfloat2 __attribute__((ext_vector_type(2)));

struct IdxTable {
    uint32_t v[CAP];
    int count;
};

constexpr IdxTable make_table() {
    IdxTable t{};
    int c = 0;
    for (int m = -HALF; m <= HALF; ++m) {
        for (int n = -HALF; n <= HALF; ++n) {
            int prod = m * n; if (prod < 0) prod = -prod;
            int am = m < 0 ? -m : m;
            int an = n < 0 ? -n : n;
            if (prod <= LIM && n >= m && (am + an) <= HALF) {
                uint32_t iu  = (uint32_t)(HALF + m);
                uint32_t iv  = (uint32_t)(HALF + n);
                uint32_t iw  = (uint32_t)(HALF + m + n);
                uint32_t sym = (m != n) ? 1u : 0u;
                t.v[c++] = iu | (iv << 8) | (iw << 16) | (sym << 24);
            }
        }
    }
    t.count = c;
    return t;
}

constexpr IdxTable HOST_TAB = make_table();
constexpr int K = HOST_TAB.count;              // = 173
static_assert(K > 0 && K <= CAP, "index table overflow");

constexpr int NB    = 32;                      // b-rows per block
constexpr int NWAVE = 4;                       // 256 threads
constexpr int RPW   = NB / NWAVE;              // 8 rows per wave
constexpr int KCH   = (K + 63) / 64;           // 3 k-slots per lane

} // namespace

__constant__ IdxTable g_tab = make_table();

template <bool WRITE_COMPLEX>
__global__ __launch_bounds__(256)
void triplet_kernel(const float2* __restrict__ Er2, const float2* __restrict__ Ei2,
                    float* __restrict__ out, int B) {
    __shared__ float4 sE[NB * MM];             // (b_local, i) -> (Er0,Er1,Ei0,Ei1)

    int b0 = blockIdx.x * NB;
    int rows = B - b0; if (rows > NB) rows = NB;
    int nent = rows * MM;
    int gbase = b0 * MM;                       // float2 index into (B,41,2)

    // Stage: float4 global loads (2 entries each), coalesced.
    {
        const float4* Er4 = reinterpret_cast<const float4*>(Er2 + gbase);
        const float4* Ei4 = reinterpret_cast<const float4*>(Ei2 + gbase);
        int npair = nent >> 1;
        for (int e = threadIdx.x; e < npair; e += 256) {
            float4 r  = Er4[e];
            float4 im = Ei4[e];
            sE[2 * e]     = make_float4(r.x, r.y, im.x, im.y);
            sE[2 * e + 1] = make_float4(r.z, r.w, im.z, im.w);
        }
        if ((nent & 1) && threadIdx.x == 0) {
            float2 r  = Er2[gbase + nent - 1];
            float2 im = Ei2[gbase + nent - 1];
            sE[nent - 1] = make_float4(r.x, r.y, im.x, im.y);
        }
    }
    __syncthreads();

    int lane = threadIdx.x & 63;
    int wave = threadIdx.x >> 6;

    // Hoist per-lane table decode: same k-slots reused for every row.
    int   offu[KCH], offv[KCH], offw[KCH];
    float symf[KCH];
    bool  act[KCH];
    #pragma unroll
    for (int j = 0; j < KCH; ++j) {
        int k = lane + 64 * j;
        act[j] = (k < K);
        uint32_t e = g_tab.v[act[j] ? k : 0];
        offu[j] = (int)(e & 0xffu);
        offv[j] = (int)((e >> 8) & 0xffu);
        offw[j] = (int)((e >> 16) & 0xffu);
        symf[j] = (e >> 24) ? 1.0f : 0.0f;
    }

    int blbeg = wave * RPW;
    #pragma unroll 2
    for (int r = 0; r < RPW; ++r) {
        int bl = blbeg + r;
        if (bl >= rows) break;
        const float4* sb = sE + bl * MM;
        size_t obase = (size_t)(b0 + bl) * 2 * K;
        #pragma unroll
        for (int j = 0; j < KCH; ++j) {
            if (!act[j]) continue;
            int k = lane + 64 * j;
            float4 u = sb[offu[j]];            // (Ur0,Ur1,Ui0,Ui1)
            float4 v = sb[offv[j]];
            float4 w = sb[offw[j]];

            float smn_r = u.x * w.x + u.z * w.z + u.y * w.y + u.w * w.w;
            float smn_i = u.z * w.x - u.x * w.z + u.w * w.y - u.y * w.w;
            float snm_r = (v.x * w.x + v.z * w.z + v.y * w.y + v.w * w.w) * symf[j];
            float snm_i = (v.z * w.x - v.x * w.z + v.w * w.y - v.y * w.w) * symf[j];

            float o0r = smn_r * v.x - smn_i * v.z + snm_r * u.x - snm_i * u.z;
            float o1r = smn_r * v.y - smn_i * v.w + snm_r * u.y - snm_i * u.w;

            if constexpr (WRITE_COMPLEX) {
                float o0i = smn_r * v.z + smn_i * v.x + snm_r * u.z + snm_i * u.x;
                float o1i = smn_r * v.w + smn_i * v.y + snm_r * u.w + snm_i * u.y;
                vfloat2* o2 = reinterpret_cast<vfloat2*>(out);
                vfloat2 a0; a0.x = o0r; a0.y = o0i;
                vfloat2 a1; a1.x = o1r; a1.y = o1i;
                __builtin_nontemporal_store(a0, &o2[obase + k]);
                __builtin_nontemporal_store(a1, &o2[obase + K + k]);
            } else {
                __builtin_nontemporal_store(o0r, &out[obase + k]);
                __builtin_nontemporal_store(o1r, &out[obase + K + k]);
            }
        }
    }
}

extern "C" void kernel_launch(void* const* d_in, const int* in_sizes, int n_in,
                              void* d_out, int out_size, void* d_ws, size_t ws_size,
                              hipStream_t stream) {
    const float2* Er2 = (const float2*)d_in[0];
    const float2* Ei2 = (const float2*)d_in[1];
    float* out = (float*)d_out;

    int B = in_sizes[0] / (2 * MM);            // (B, 41, 2) float32
    int grid = (B + NB - 1) / NB;
    int block = 256;

    if ((long)out_size == (long)B * 2 * K * 2) {
        triplet_kernel<true><<<grid, block, 0, stream>>>(Er2, Ei2, out, B);
    } else {
        triplet_kernel<false><<<grid, block, 0, stream>>>(Er2, Ei2, out, B);
    }
}

// Round 6
// 129.924 us; speedup vs baseline: 1.0865x; 1.0865x over previous
//
#include <hip/hip_runtime.h>
#include <cstdint>
#include <cstddef>

// ---------------------------------------------------------------------------
// TripletFeatures: out[b,c,k] = S_mn * E[p+n,c] + (m!=n) * S_nm * E[p+m,c]
//   S_xy = sum_c E[p+x,c] * conj(E[p+x+y,c]),  E = E_real + i*E_imag, p=20
// R5 == R4 resubmit (acquisition timeout, never ran) + fix a typo in the
// dead WRITE_COMPLEX branch (o1i last term u.w -> u.y).
// R4: R1 structure (LDS-staged NB=32, plain stores — nontemporal REVERTED,
// it regressed ~11us) + float4 staging loads + fully-unrolled branch-free
// row loop for the exact rows==NB case (B is a multiple of 32).
// ---------------------------------------------------------------------------

namespace {

constexpr int MM   = 41;   // M
constexpr int HALF = 20;   // M//2
constexpr int LIM  = 20;   // RHO*L//2
constexpr int CAP  = 256;

struct IdxTable {
    uint32_t v[CAP];
    int count;
};

constexpr IdxTable make_table() {
    IdxTable t{};
    int c = 0;
    for (int m = -HALF; m <= HALF; ++m) {
        for (int n = -HALF; n <= HALF; ++n) {
            int prod = m * n; if (prod < 0) prod = -prod;
            int am = m < 0 ? -m : m;
            int an = n < 0 ? -n : n;
            if (prod <= LIM && n >= m && (am + an) <= HALF) {
                uint32_t iu  = (uint32_t)(HALF + m);
                uint32_t iv  = (uint32_t)(HALF + n);
                uint32_t iw  = (uint32_t)(HALF + m + n);
                uint32_t sym = (m != n) ? 1u : 0u;
                t.v[c++] = iu | (iv << 8) | (iw << 16) | (sym << 24);
            }
        }
    }
    t.count = c;
    return t;
}

constexpr IdxTable HOST_TAB = make_table();
constexpr int K = HOST_TAB.count;              // = 173
static_assert(K > 0 && K <= CAP, "index table overflow");

constexpr int NB    = 32;                      // b-rows per block
constexpr int NWAVE = 4;                       // 256 threads
constexpr int RPW   = NB / NWAVE;              // 8 rows per wave
constexpr int KCH   = (K + 63) / 64;           // 3 k-slots per lane

} // namespace

__constant__ IdxTable g_tab = make_table();

template <bool WRITE_COMPLEX>
__global__ __launch_bounds__(256)
void triplet_kernel(const float2* __restrict__ Er2, const float2* __restrict__ Ei2,
                    float* __restrict__ out, int B) {
    __shared__ float4 sE[NB * MM];             // (b_local, i) -> (Er0,Er1,Ei0,Ei1)

    int b0 = blockIdx.x * NB;
    int rows = B - b0; if (rows > NB) rows = NB;
    int nent = rows * MM;
    int gbase = b0 * MM;                       // float2 index into (B,41,2)

    // Stage: float4 global loads (2 entries each), coalesced.
    {
        const float4* Er4 = reinterpret_cast<const float4*>(Er2 + gbase);
        const float4* Ei4 = reinterpret_cast<const float4*>(Ei2 + gbase);
        int npair = nent >> 1;
        for (int e = threadIdx.x; e < npair; e += 256) {
            float4 r  = Er4[e];
            float4 im = Ei4[e];
            sE[2 * e]     = make_float4(r.x, r.y, im.x, im.y);
            sE[2 * e + 1] = make_float4(r.z, r.w, im.z, im.w);
        }
        if ((nent & 1) && threadIdx.x == 0) {
            float2 r  = Er2[gbase + nent - 1];
            float2 im = Ei2[gbase + nent - 1];
            sE[nent - 1] = make_float4(r.x, r.y, im.x, im.y);
        }
    }
    __syncthreads();

    int lane = threadIdx.x & 63;
    int wave = threadIdx.x >> 6;

    // Hoist per-lane table decode: same k-slots reused for every row.
    int   offu[KCH], offv[KCH], offw[KCH];
    float symf[KCH];
    bool  act[KCH];
    #pragma unroll
    for (int j = 0; j < KCH; ++j) {
        int k = lane + 64 * j;
        act[j] = (k < K);
        uint32_t e = g_tab.v[act[j] ? k : 0];
        offu[j] = (int)(e & 0xffu);
        offv[j] = (int)((e >> 8) & 0xffu);
        offw[j] = (int)((e >> 16) & 0xffu);
        symf[j] = (e >> 24) ? 1.0f : 0.0f;
    }

    auto do_row = [&](int bl) {
        const float4* sb = sE + bl * MM;
        size_t obase = (size_t)(b0 + bl) * 2 * K;
        #pragma unroll
        for (int j = 0; j < KCH; ++j) {
            if (!act[j]) continue;
            int k = lane + 64 * j;
            float4 u = sb[offu[j]];            // (Ur0,Ur1,Ui0,Ui1)
            float4 v = sb[offv[j]];
            float4 w = sb[offw[j]];

            float smn_r = u.x * w.x + u.z * w.z + u.y * w.y + u.w * w.w;
            float smn_i = u.z * w.x - u.x * w.z + u.w * w.y - u.y * w.w;
            float snm_r = (v.x * w.x + v.z * w.z + v.y * w.y + v.w * w.w) * symf[j];
            float snm_i = (v.z * w.x - v.x * w.z + v.w * w.y - v.y * w.w) * symf[j];

            float o0r = smn_r * v.x - smn_i * v.z + snm_r * u.x - snm_i * u.z;
            float o1r = smn_r * v.y - smn_i * v.w + snm_r * u.y - snm_i * u.w;

            if constexpr (WRITE_COMPLEX) {
                float o0i = smn_r * v.z + smn_i * v.x + snm_r * u.z + snm_i * u.x;
                float o1i = smn_r * v.w + smn_i * v.y + snm_r * u.w + snm_i * u.y;
                float2* o2 = reinterpret_cast<float2*>(out);
                o2[obase + k]     = make_float2(o0r, o0i);
                o2[obase + K + k] = make_float2(o1r, o1i);
            } else {
                out[obase + k]     = o0r;
                out[obase + K + k] = o1r;
            }
        }
    };

    if (rows == NB) {
        // Common case (B % 32 == 0): branch-free, fully unrolled for ILP.
        #pragma unroll
        for (int r = 0; r < RPW; ++r)
            do_row(wave * RPW + r);
    } else {
        for (int r = 0; r < RPW; ++r) {
            int bl = wave * RPW + r;
            if (bl < rows) do_row(bl);
        }
    }
}

extern "C" void kernel_launch(void* const* d_in, const int* in_sizes, int n_in,
                              void* d_out, int out_size, void* d_ws, size_t ws_size,
                              hipStream_t stream) {
    const float2* Er2 = (const float2*)d_in[0];
    const float2* Ei2 = (const float2*)d_in[1];
    float* out = (float*)d_out;

    int B = in_sizes[0] / (2 * MM);            // (B, 41, 2) float32
    int grid = (B + NB - 1) / NB;
    int block = 256;

    if ((long)out_size == (long)B * 2 * K * 2) {
        triplet_kernel<true><<<grid, block, 0, stream>>>(Er2, Ei2, out, B);
    } else {
        triplet_kernel<false><<<grid, block, 0, stream>>>(Er2, Ei2, out, B);
    }
}

// Round 7
// 128.481 us; speedup vs baseline: 1.0987x; 1.0112x over previous
//
#include <hip/hip_runtime.h>
#include <cstdint>
#include <cstddef>

// ---------------------------------------------------------------------------
// TripletFeatures: out[b,c,k] = S_mn * E[p+n,c] + (m!=n) * S_nm * E[p+m,c]
//   S_xy = sum_c E[p+x,c] * conj(E[p+x+y,c]),  E = E_real + i*E_imag, p=20
// R6: R5 with NB 32 -> 16 (10.5 KB LDS/block, 4096 blocks) to raise
// occupancy toward 32 waves/CU and overlap staging of new blocks with the
// store-heavy tails of resident ones. Traffic unchanged; pure overlap play.
// ---------------------------------------------------------------------------

namespace {

constexpr int MM   = 41;   // M
constexpr int HALF = 20;   // M//2
constexpr int LIM  = 20;   // RHO*L//2
constexpr int CAP  = 256;

struct IdxTable {
    uint32_t v[CAP];
    int count;
};

constexpr IdxTable make_table() {
    IdxTable t{};
    int c = 0;
    for (int m = -HALF; m <= HALF; ++m) {
        for (int n = -HALF; n <= HALF; ++n) {
            int prod = m * n; if (prod < 0) prod = -prod;
            int am = m < 0 ? -m : m;
            int an = n < 0 ? -n : n;
            if (prod <= LIM && n >= m && (am + an) <= HALF) {
                uint32_t iu  = (uint32_t)(HALF + m);
                uint32_t iv  = (uint32_t)(HALF + n);
                uint32_t iw  = (uint32_t)(HALF + m + n);
                uint32_t sym = (m != n) ? 1u : 0u;
                t.v[c++] = iu | (iv << 8) | (iw << 16) | (sym << 24);
            }
        }
    }
    t.count = c;
    return t;
}

constexpr IdxTable HOST_TAB = make_table();
constexpr int K = HOST_TAB.count;              // = 173
static_assert(K > 0 && K <= CAP, "index table overflow");

constexpr int NB    = 16;                      // b-rows per block
constexpr int NWAVE = 4;                       // 256 threads
constexpr int RPW   = NB / NWAVE;              // 4 rows per wave
constexpr int KCH   = (K + 63) / 64;           // 3 k-slots per lane

} // namespace

__constant__ IdxTable g_tab = make_table();

template <bool WRITE_COMPLEX>
__global__ __launch_bounds__(256)
void triplet_kernel(const float2* __restrict__ Er2, const float2* __restrict__ Ei2,
                    float* __restrict__ out, int B) {
    __shared__ float4 sE[NB * MM];             // (b_local, i) -> (Er0,Er1,Ei0,Ei1)

    int b0 = blockIdx.x * NB;
    int rows = B - b0; if (rows > NB) rows = NB;
    int nent = rows * MM;
    int gbase = b0 * MM;                       // float2 index into (B,41,2)

    // Stage: float4 global loads (2 entries each), coalesced.
    {
        const float4* Er4 = reinterpret_cast<const float4*>(Er2 + gbase);
        const float4* Ei4 = reinterpret_cast<const float4*>(Ei2 + gbase);
        int npair = nent >> 1;
        for (int e = threadIdx.x; e < npair; e += 256) {
            float4 r  = Er4[e];
            float4 im = Ei4[e];
            sE[2 * e]     = make_float4(r.x, r.y, im.x, im.y);
            sE[2 * e + 1] = make_float4(r.z, r.w, im.z, im.w);
        }
        if ((nent & 1) && threadIdx.x == 0) {
            float2 r  = Er2[gbase + nent - 1];
            float2 im = Ei2[gbase + nent - 1];
            sE[nent - 1] = make_float4(r.x, r.y, im.x, im.y);
        }
    }
    __syncthreads();

    int lane = threadIdx.x & 63;
    int wave = threadIdx.x >> 6;

    // Hoist per-lane table decode: same k-slots reused for every row.
    int   offu[KCH], offv[KCH], offw[KCH];
    float symf[KCH];
    bool  act[KCH];
    #pragma unroll
    for (int j = 0; j < KCH; ++j) {
        int k = lane + 64 * j;
        act[j] = (k < K);
        uint32_t e = g_tab.v[act[j] ? k : 0];
        offu[j] = (int)(e & 0xffu);
        offv[j] = (int)((e >> 8) & 0xffu);
        offw[j] = (int)((e >> 16) & 0xffu);
        symf[j] = (e >> 24) ? 1.0f : 0.0f;
    }

    auto do_row = [&](int bl) {
        const float4* sb = sE + bl * MM;
        size_t obase = (size_t)(b0 + bl) * 2 * K;
        #pragma unroll
        for (int j = 0; j < KCH; ++j) {
            if (!act[j]) continue;
            int k = lane + 64 * j;
            float4 u = sb[offu[j]];            // (Ur0,Ur1,Ui0,Ui1)
            float4 v = sb[offv[j]];
            float4 w = sb[offw[j]];

            float smn_r = u.x * w.x + u.z * w.z + u.y * w.y + u.w * w.w;
            float smn_i = u.z * w.x - u.x * w.z + u.w * w.y - u.y * w.w;
            float snm_r = (v.x * w.x + v.z * w.z + v.y * w.y + v.w * w.w) * symf[j];
            float snm_i = (v.z * w.x - v.x * w.z + v.w * w.y - v.y * w.w) * symf[j];

            float o0r = smn_r * v.x - smn_i * v.z + snm_r * u.x - snm_i * u.z;
            float o1r = smn_r * v.y - smn_i * v.w + snm_r * u.y - snm_i * u.w;

            if constexpr (WRITE_COMPLEX) {
                float o0i = smn_r * v.z + smn_i * v.x + snm_r * u.z + snm_i * u.x;
                float o1i = smn_r * v.w + smn_i * v.y + snm_r * u.w + snm_i * u.y;
                float2* o2 = reinterpret_cast<float2*>(out);
                o2[obase + k]     = make_float2(o0r, o0i);
                o2[obase + K + k] = make_float2(o1r, o1i);
            } else {
                out[obase + k]     = o0r;
                out[obase + K + k] = o1r;
            }
        }
    };

    if (rows == NB) {
        // Common case (B % 16 == 0): branch-free, fully unrolled for ILP.
        #pragma unroll
        for (int r = 0; r < RPW; ++r)
            do_row(wave * RPW + r);
    } else {
        for (int r = 0; r < RPW; ++r) {
            int bl = wave * RPW + r;
            if (bl < rows) do_row(bl);
        }
    }
}

extern "C" void kernel_launch(void* const* d_in, const int* in_sizes, int n_in,
                              void* d_out, int out_size, void* d_ws, size_t ws_size,
                              hipStream_t stream) {
    const float2* Er2 = (const float2*)d_in[0];
    const float2* Ei2 = (const float2*)d_in[1];
    float* out = (float*)d_out;

    int B = in_sizes[0] / (2 * MM);            // (B, 41, 2) float32
    int grid = (B + NB - 1) / NB;
    int block = 256;

    if ((long)out_size == (long)B * 2 * K * 2) {
        triplet_kernel<true><<<grid, block, 0, stream>>>(Er2, Ei2, out, B);
    } else {
        triplet_kernel<false><<<grid, block, 0, stream>>>(Er2, Ei2, out, B);
    }
}